// Round 2
// baseline (232.319 us; speedup 1.0000x reference)
//
#include <hip/hip_runtime.h>

// IDWT reconstruction layer.
// x: (B=16, L=32768, 64) f32, channels [0,32)=approx, [32,64)=detail.
// out: (16, 2L=65536, 32) f32.
//
// out[b, 2p,   c] = sum_t lo[2t+1]*A[p-1+t] + hi[2t+1]*D[p-1+t]
// out[b, 2p+1, c] = sum_t lo[2t  ]*A[p-1+t] + hi[2t  ]*D[p-1+t]
// (t in 0..3; rows outside [0,L) contribute zero)
//
// Each thread: channel group g (4 channels) x 4 consecutive p values.
// Loads rows p0-1 .. p0+5 (7 A + 7 D float4s) once, emits 8 output rows.
// 14 loads : 8 stores (vs 32 : 8 for the 1-p-per-thread version).

#define B_    16
#define L_    32768
#define CIN_  64
#define COUT_ 32
#define PT    4          // p values per thread

typedef float vf4 __attribute__((ext_vector_type(4)));

__global__ __launch_bounds__(256) void idwt_kernel(
    const float* __restrict__ x,
    const float* __restrict__ rec_lo,
    const float* __restrict__ rec_hi,
    float* __restrict__ out)
{
    const int tid = blockIdx.x * blockDim.x + threadIdx.x;
    const int g   = tid & 7;                 // channel group (c = 4g)
    const int q   = tid >> 3;                // (b, p-tile)
    const int pt  = q & (L_ / PT - 1);       // L_/PT = 8192 = 2^13
    const int b   = q >> 13;
    const int p0  = pt * PT;

    const float* xb = x + (size_t)b * (L_ * CIN_) + (g << 2);

    // Load the 7-row halo slab once, branch-free (clamp + select-zero).
    float A[PT + 3][4], D[PT + 3][4];
#pragma unroll
    for (int t = 0; t < PT + 3; ++t) {
        const int j  = p0 - 1 + t;
        const bool ok = (j >= 0) && (j < L_);
        const int jc = ok ? j : 0;           // clamped, always in-bounds
        const vf4 a = *(const vf4*)(xb + (size_t)jc * CIN_);
        const vf4 d = *(const vf4*)(xb + (size_t)jc * CIN_ + COUT_);
#pragma unroll
        for (int c = 0; c < 4; ++c) {
            A[t][c] = ok ? a[c] : 0.f;
            D[t][c] = ok ? d[c] : 0.f;
        }
    }

    // Wave-uniform filter loads (scalarized to s_load by the compiler).
    float lo[8], hi[8];
#pragma unroll
    for (int k = 0; k < 8; ++k) { lo[k] = rec_lo[k]; hi[k] = rec_hi[k]; }

    float* orow = out + (size_t)(b * (2 * L_) + 2 * p0) * COUT_ + (g << 2);
#pragma unroll
    for (int k = 0; k < PT; ++k) {
        vf4 ev, od;
#pragma unroll
        for (int c = 0; c < 4; ++c) {
            float e = 0.f, o = 0.f;
#pragma unroll
            for (int t = 0; t < 4; ++t) {
                e = fmaf(lo[2 * t + 1], A[k + t][c], e);
                e = fmaf(hi[2 * t + 1], D[k + t][c], e);
                o = fmaf(lo[2 * t],     A[k + t][c], o);
                o = fmaf(hi[2 * t],     D[k + t][c], o);
            }
            ev[c] = e; od[c] = o;
        }
        // Output is write-once: nontemporal keeps stores from evicting
        // the reused input rows in L2.
        __builtin_nontemporal_store(ev, (vf4*)(orow + (2 * k) * COUT_));
        __builtin_nontemporal_store(od, (vf4*)(orow + (2 * k + 1) * COUT_));
    }
}

extern "C" void kernel_launch(void* const* d_in, const int* in_sizes, int n_in,
                              void* d_out, int out_size, void* d_ws, size_t ws_size,
                              hipStream_t stream) {
    const float* x      = (const float*)d_in[0];
    const float* rec_lo = (const float*)d_in[1];
    const float* rec_hi = (const float*)d_in[2];
    float* out = (float*)d_out;

    const int total_threads = B_ * (L_ / PT) * (COUT_ / 4);  // 1,048,576
    const int block = 256;
    idwt_kernel<<<total_threads / block, block, 0, stream>>>(x, rec_lo, rec_hi, out);
}